// Round 15
// baseline (718.502 us; speedup 1.0000x reference)
//
#include <hip/hip_runtime.h>

#define NENT  100000
#define NREL  400
#define EMB   100
#define NF    51
#define FCMP  102
#define OUTC  200
#define NEDGE 500000
#define HALFE 250000
#define BATCH 512
#define POSN  196
#define FCK   39200
#define BN_EPS 1e-5f
#define CAP   16
#define KSPLIT 175
#define NCOL8  208   // 13*16 col frags in fc
#define FCOUT  106496  // 512*208

// ---- workspace layout (floats). Peak ~204.3 MB.
// Fa/accIn/accOut: f16 [NENT][102] interleaved (re,im) -> u32 word f = (re_f,im_f).
// z1 is POS-MAJOR [512][196][200] f16 (k = pos*200+ch); fcw_h permuted to match.
// Lifetimes: Fa16 dead after k_fused_x_mfma -> x_h overlays it.
//            accIn dead after k_fused_x_mfma -> z1h (f16) overlays it.
//            accOut dead after k_fused_x_mfma -> fcw_h (f16) overlays it.
//            IMG region: DFTH table (early) -> img (mid) -> z_h (late).
//            XBUF region: bucket ints (early) -> xpre f16 (mid) -> fc partials (late).
static constexpr size_t OFF_FA     = 0;          // [NENT][51] u32 words (f16 cplx)
static constexpr size_t OFF_XH     = 0;          // [NENT][200] f16 overlay
static constexpr size_t OFF_ACCIN  = 10200000;   // [NENT][51] u32 words (f16 cplx)
static constexpr size_t OFF_Z1H    = 10200000;   // [512][196][200] f16 overlay
static constexpr size_t OFF_ACCOUT = 20400000;   // [NENT][51] u32 words (f16 cplx)
static constexpr size_t OFF_FCWH   = 20400000;   // [200][39200] f16 overlay (k = pos*200+ch)
static constexpr size_t OFF_XBUF   = 30600000;   // bucket ints / xpre f16 / fc partials
static constexpr size_t OFF_FB     = 50600000;   // [NREL][51] words
static constexpr size_t OFF_FL     = 50640800;   // [51] words (+pad)
static constexpr size_t OFF_BIGBT  = 50640928;   // [208][336] f16 = 34944 floats (zeroed)
static constexpr size_t OFF_R      = 50675872;   // [400][200]
static constexpr size_t OFF_IMG    = 50755872;   // [512][400]
static constexpr size_t OFF_DFTH   = 50755872;   // [112][128] f16 overlay (early-only)
static constexpr size_t OFF_ZH     = 50755872;   // [512][200] f16 overlay (late)
static constexpr size_t OFF_DFTC   = 50960672;   // [100][51]
static constexpr size_t OFF_DFTS   = 50965772;   // [100][51]
static constexpr size_t OFF_Z      = 50970872;   // [512][200] (written fully by k_fc_reduce)
static constexpr size_t OFF_COLSUM = OFF_Z + 102400;   // memset region starts here
static constexpr size_t OFF_COLSS  = OFF_COLSUM + 200;
static constexpr size_t OFF_BN1    = OFF_COLSS + 200;   // 2 (+pad to 8)
static constexpr size_t OFF_CHSUM  = OFF_BN1 + 8;
static constexpr size_t OFF_CHSS   = OFF_CHSUM + 200;
static constexpr size_t WS_END     = OFF_CHSS + 200;

// bucket layout (ints, base = ws + OFF_XBUF). memset covers CNT+OVFN.
#define NBUCK 200000
static constexpr size_t BK_CNT   = 0;          // [NBUCK]
static constexpr size_t BK_OVFN  = 200000;     // [1]
static constexpr size_t BK_OVF   = 200004;     // [NEDGE] edge-id overflow list (normally empty)
static constexpr size_t BK_SLOT  = 700008;     // uint2[NBUCK*CAP]

typedef __attribute__((ext_vector_type(8))) _Float16 f16x8;
typedef __attribute__((ext_vector_type(4))) _Float16 f16x4;
typedef __attribute__((ext_vector_type(4))) float f32x4;

__device__ inline unsigned int pkc(float re, float im) {
  union { _Float16 h[2]; unsigned int u; } c;
  c.h[0] = (_Float16)re; c.h[1] = (_Float16)im;
  return c.u;
}
__device__ inline float2 unpk(unsigned int w) {
  union { unsigned int u; _Float16 h[2]; } c; c.u = w;
  return make_float2((float)c.h[0], (float)c.h[1]);
}
__device__ inline float sigf(float v) {
  return __builtin_amdgcn_rcpf(1.0f + __expf(-v));
}

// ---------------- DFT twiddle tables (f32, for k_wtilde + small rffts) ----------------
__global__ void k_tables(float* __restrict__ ws) {
  int i = blockIdx.x * 256 + threadIdx.x;
  if (i >= EMB * NF) return;
  int j = i / NF, f = i - j * NF;
  int m = (j * f) % EMB;
  float ang = (float)m * 0.06283185307179586f;  // 2*pi/100
  ws[OFF_DFTC + i] = cosf(ang);
  ws[OFF_DFTS + i] = sinf(ang);
}

// ---------------- DT[112][128] f16 ----------------
__global__ void k_dfth(_Float16* __restrict__ DT) {
  int i = blockIdx.x * 256 + threadIdx.x;
  if (i >= 112 * 128) return;
  int c = i >> 7, k = i & 127;
  float v = 0.f;
  if (c < FCMP && k < EMB) {
    int f = c >> 1;
    int m = (k * f) % EMB;
    float ang = (float)m * 0.06283185307179586f;
    v = (c & 1) ? -sinf(ang) : cosf(ang);
  }
  DT[i] = (_Float16)v;
}

// ---------------- rfft of ent_emb via f16 MFMA ----------------
__global__ void __launch_bounds__(256) k_rfft_mfma(const float* __restrict__ A,
                                                   const _Float16* __restrict__ DT,
                                                   _Float16* __restrict__ Fa) {
  int t = threadIdx.x;
  int w = t >> 6, l = t & 63;
  int lr = l & 15, kg = l >> 4;
  size_t row0 = (size_t)blockIdx.x * 128 + w * 32;
  f32x4 acc[2][7];
  #pragma unroll
  for (int i = 0; i < 2; ++i)
    #pragma unroll
    for (int j = 0; j < 7; ++j) acc[i][j] = (f32x4){0.f, 0.f, 0.f, 0.f};

  #pragma unroll
  for (int st = 0; st < 4; ++st) {
    int koff = st * 32 + kg * 8;
    f16x8 a[2];
    #pragma unroll
    for (int i = 0; i < 2; ++i) {
      size_t row = row0 + i * 16 + lr;
      if (row >= NENT) row = NENT - 1;  // clamp for load; store masked
      f16x8 h;
      if (st < 3) {
        const float* p = A + row * EMB + koff;
        float4 p0 = *(const float4*)p;
        float4 p1 = *(const float4*)(p + 4);
        h[0] = (_Float16)p0.x; h[1] = (_Float16)p0.y; h[2] = (_Float16)p0.z; h[3] = (_Float16)p0.w;
        h[4] = (_Float16)p1.x; h[5] = (_Float16)p1.y; h[6] = (_Float16)p1.z; h[7] = (_Float16)p1.w;
      } else if (kg == 0) {  // k = 96..99 valid
        float4 p0 = *(const float4*)(A + row * EMB + 96);
        h[0] = (_Float16)p0.x; h[1] = (_Float16)p0.y; h[2] = (_Float16)p0.z; h[3] = (_Float16)p0.w;
        h[4] = (_Float16)0.f; h[5] = (_Float16)0.f; h[6] = (_Float16)0.f; h[7] = (_Float16)0.f;
      } else {
        h = (f16x8)0;
      }
      a[i] = h;
    }
    f16x8 b[7];
    #pragma unroll
    for (int j = 0; j < 7; ++j)
      b[j] = *(const f16x8*)(DT + (size_t)(j * 16 + lr) * 128 + koff);
    #pragma unroll
    for (int i = 0; i < 2; ++i)
      #pragma unroll
      for (int j = 0; j < 7; ++j)
        acc[i][j] = __builtin_amdgcn_mfma_f32_16x16x32_f16(a[i], b[j], acc[i][j], 0, 0, 0);
  }

  #pragma unroll
  for (int i = 0; i < 2; ++i) {
    #pragma unroll
    for (int j = 0; j < 7; ++j) {
      int col = j * 16 + lr;
      if (col < FCMP) {
        #pragma unroll
        for (int r = 0; r < 4; ++r) {
          size_t row = row0 + i * 16 + kg * 4 + r;
          if (row < NENT) Fa[row * FCMP + col] = (_Float16)acc[i][j][r];
        }
      }
    }
  }
}

// ---------------- rfft rows -> f16 cplx words (small: rel_emb, loop_rel) ----------------
__global__ void k_rfft(const float* __restrict__ src, unsigned int* __restrict__ dst,
                       const float* __restrict__ dftc, const float* __restrict__ dfts,
                       int nrows) {
  __shared__ float arow[4][EMB];
  int g = threadIdx.x >> 6;
  int lane = threadIdx.x & 63;
  int row = blockIdx.x * 4 + g;
  if (row < nrows) {
    for (int j = lane; j < EMB; j += 64) arow[g][j] = src[(size_t)row * EMB + j];
  }
  __syncthreads();
  if (row < nrows && lane < NF) {
    float re = 0.f, im = 0.f;
    for (int j = 0; j < EMB; ++j) {
      float a = arow[g][j];
      re += a * dftc[j * NF + lane];
      im -= a * dfts[j * NF + lane];
    }
    dst[(size_t)row * NF + lane] = pkc(re, im);
  }
}

// ---------------- fold irfft + weight + 1/3 into BigBT[208][336] f16 ----------------
__global__ void k_wtilde(const float* __restrict__ in_w, const float* __restrict__ out_w,
                         const float* __restrict__ loop_w, float* __restrict__ ws) {
  int id = blockIdx.x * 256 + threadIdx.x;
  if (id >= NF * OUTC) return;
  int f = id / OUTC, o = id - f * OUTC;
  const float* dftc = ws + OFF_DFTC;
  const float* dfts = ws + OFF_DFTS;
  float ci = 0, si = 0, co = 0, so = 0, cl = 0, sl = 0;
  for (int k = 0; k < EMB; ++k) {
    float c = dftc[k * NF + f], s = dfts[k * NF + f];
    float wi = in_w[k * OUTC + o], wo = out_w[k * OUTC + o], wl = loop_w[k * OUTC + o];
    ci += c * wi; si += s * wi;
    co += c * wo; so += s * wo;
    cl += c * wl; sl += s * wl;
  }
  bool ends = (f == 0) || (f == NF - 1);
  float mult = ends ? 1.0f : 2.0f;
  const float inv3n = 1.0f / (3.0f * (float)EMB);
  _Float16* bt = (_Float16*)(ws + OFF_BIGBT);
  size_t ro = (size_t)o * 336;
  bt[ro + 102 + 2 * f]     = (_Float16)(mult * ci * inv3n);
  bt[ro + 102 + 2 * f + 1] = (_Float16)(ends ? 0.f : (-2.0f * si * inv3n));
  bt[ro + 204 + 2 * f]     = (_Float16)(mult * co * inv3n);
  bt[ro + 204 + 2 * f + 1] = (_Float16)(ends ? 0.f : (-2.0f * so * inv3n));
  float wlre = mult * cl * inv3n;
  float wlim = ends ? 0.f : (-2.0f * sl * inv3n);
  float2 fl = unpk(((const unsigned int*)(ws + OFF_FL))[f]);
  bt[ro + 2 * f]     = (_Float16)(fl.x * wlre + fl.y * wlim);
  bt[ro + 2 * f + 1] = (_Float16)(fl.y * wlre - fl.x * wlim);
}

// ---------------- bucket build ----------------
__global__ void k_bucket(const int* __restrict__ edst, const int* __restrict__ esrc,
                         const int* __restrict__ etyp, const float* __restrict__ enorm,
                         int* __restrict__ cnt, uint2* __restrict__ slot,
                         int* __restrict__ ovfn, int* __restrict__ ovf) {
  int e = blockIdx.x * 256 + threadIdx.x;
  if (e >= NEDGE) return;
  int b = (e < HALFE ? 0 : NENT) + edst[e];
  int pos = atomicAdd(&cnt[b], 1);
  if (pos < CAP) {
    unsigned int p = (unsigned int)esrc[e] | ((unsigned int)etyp[e] << 17);
    slot[(size_t)b * CAP + pos] = make_uint2(p, __float_as_uint(enorm[e]));
  } else {  // statistically ~never; correctness fallback
    int oi = atomicAdd(ovfn, 1);
    if (oi < NEDGE) ovf[oi] = e;
  }
}

// ---------------- gather-aggregate (no atomics), 4-deep MLP unroll, f16 packed output ------
__global__ void __launch_bounds__(256) k_agg(const unsigned int* __restrict__ faw,
                                             const unsigned int* __restrict__ fbw,
                                             const int* __restrict__ cnt,
                                             const uint2* __restrict__ slot,
                                             unsigned int* __restrict__ accIn,
                                             unsigned int* __restrict__ accOut) {
  int g = threadIdx.x >> 6;          // 4 waves: (d0,in),(d0,out),(d0+1,in),(d0+1,out)
  int lane = threadIdx.x & 63;
  int d = blockIdx.x * 2 + (g >> 1);
  int sub = g & 1;
  int bucket = sub * NENT + d;
  int n = cnt[bucket];
  if (n > CAP) n = CAP;
  const uint2* sl = slot + (size_t)bucket * CAP;
  uint2 my = make_uint2(0u, 0u);
  if (lane < n) my = sl[lane];       // lane-parallel slot prefetch
  float ar = 0.f, ai = 0.f;
  for (int i = 0; i < n; i += 4) {   // 4-wide: loads for u=0..3 independent -> 4-deep MLP
    #pragma unroll
    for (int u = 0; u < 4; ++u) {
      int iu = i + u;
      int ic = (iu < n) ? iu : (n - 1);          // clamp (n>=1 inside loop)
      unsigned int p = (unsigned int)__shfl((int)my.x, ic);
      float nor = __uint_as_float((unsigned int)__shfl((int)my.y, ic));
      if (iu >= n) nor = 0.f;                    // mask duplicates
      int s = (int)(p & 0x1FFFFu);
      int ty = (int)(p >> 17);
      if (lane < NF) {
        float2 fa = unpk(faw[(size_t)s * NF + lane]);
        float2 fb = unpk(fbw[(size_t)ty * NF + lane]);
        ar += (fa.x * fb.x + fa.y * fb.y) * nor;  // conj(Fa)*Fb real
        ai += (fa.x * fb.y - fa.y * fb.x) * nor;  // imag
      }
    }
  }
  if (lane < NF) {
    unsigned int* dst = sub ? accOut : accIn;
    dst[(size_t)d * NF + lane] = pkc(ar, ai);
  }
}

// ---------------- overflow replay (normally empty): CAS add on packed f16 words ----------------
__global__ void k_ovf(const unsigned int* __restrict__ faw, const unsigned int* __restrict__ fbw,
                      const int* __restrict__ esrc, const int* __restrict__ edst,
                      const int* __restrict__ etyp, const float* __restrict__ enorm,
                      const int* __restrict__ ovfn, const int* __restrict__ ovf,
                      unsigned int* __restrict__ accIn, unsigned int* __restrict__ accOut) {
  int sub = threadIdx.x >> 6;
  int l = threadIdx.x & 63;
  if (l >= NF) return;
  int n = *ovfn;
  if (n > NEDGE) n = NEDGE;
  for (int j = blockIdx.x * 4 + sub; j < n; j += gridDim.x * 4) {
    int e = ovf[j];
    int s = esrc[e], d = edst[e], ty = etyp[e];
    float nor = enorm[e];
    float2 fa = unpk(faw[(size_t)s * NF + l]);
    float2 fb = unpk(fbw[(size_t)ty * NF + l]);
    float vr = (fa.x * fb.x + fa.y * fb.y) * nor;
    float vi = (fa.x * fb.y - fa.y * fb.x) * nor;
    unsigned int* addr = ((e < HALFE) ? accIn : accOut) + (size_t)d * NF + l;
    unsigned int old = *addr, assumed;
    do {
      assumed = old;
      float2 cur = unpk(assumed);
      old = atomicCAS(addr, assumed, pkc(cur.x + vr, cur.y + vi));
    } while (old != assumed);
  }
}

// ---------------- r = rel_emb @ w_rel ----------------
__global__ void k_relmat(const float* __restrict__ rel_emb, const float* __restrict__ w_rel,
                         float* __restrict__ r) {
  int id = blockIdx.x * 256 + threadIdx.x;
  if (id >= NREL * OUTC) return;
  int rr = id / OUTC, o = id - rr * OUTC;
  float acc = 0.f;
  for (int k = 0; k < EMB; ++k) acc += rel_emb[rr * EMB + k] * w_rel[k * OUTC + o];
  r[id] = acc;
}

// ---------------- x_pre = [Fa16 | accIn16 | accOut16] @ BigBT.T via f16 MFMA -> f16 xpre ------
// All 3 segments are f16 [NENT][102] rows; uniform loads, tail step masked.
__global__ void __launch_bounds__(256) k_fused_x_mfma(const float* __restrict__ ws,
                                                      _Float16* __restrict__ xpre) {
  int t = threadIdx.x;
  int w = t >> 6, l = t & 63;
  int lr = l & 15, kg = l >> 4;
  size_t row0 = (size_t)blockIdx.x * 128 + w * 32;
  const _Float16* BT = (const _Float16*)(ws + OFF_BIGBT);
  const _Float16* segp[3] = {(const _Float16*)(ws + OFF_FA),
                             (const _Float16*)(ws + OFF_ACCIN),
                             (const _Float16*)(ws + OFF_ACCOUT)};
  f32x4 acc[2][13];
  #pragma unroll
  for (int i = 0; i < 2; ++i)
    #pragma unroll
    for (int j = 0; j < 13; ++j) acc[i][j] = (f32x4){0.f, 0.f, 0.f, 0.f};

  #pragma unroll
  for (int seg = 0; seg < 3; ++seg) {
    const _Float16* P = segp[seg];
    #pragma unroll
    for (int st = 0; st < 4; ++st) {
      int koff = st * 32 + kg * 8;
      f16x8 a[2];
      #pragma unroll
      for (int i = 0; i < 2; ++i) {
        size_t row = row0 + i * 16 + lr;
        f16x8 h = *(const f16x8*)(P + row * FCMP + koff);
        if (st == 3) {
          #pragma unroll
          for (int e = 0; e < 8; ++e)
            if (koff + e >= FCMP) h[e] = (_Float16)0.f;
        }
        a[i] = h;
      }
      f16x8 b[13];
      #pragma unroll
      for (int j = 0; j < 13; ++j)
        b[j] = *(const f16x8*)(BT + (size_t)(j * 16 + lr) * 336 + seg * FCMP + koff);
      #pragma unroll
      for (int i = 0; i < 2; ++i)
        #pragma unroll
        for (int j = 0; j < 13; ++j)
          acc[i][j] = __builtin_amdgcn_mfma_f32_16x16x32_f16(a[i], b[j], acc[i][j], 0, 0, 0);
    }
  }

  #pragma unroll
  for (int i = 0; i < 2; ++i) {
    #pragma unroll
    for (int j = 0; j < 13; ++j) {
      int col = j * 16 + lr;
      if (col < OUTC) {
        #pragma unroll
        for (int r = 0; r < 4; ++r) {
          size_t row = row0 + i * 16 + kg * 4 + r;
          if (row < NENT) xpre[row * OUTC + col] = (_Float16)acc[i][j][r];
        }
      }
    }
  }
}

// ---------------- column stats of xpre (f16) ----------------
__global__ void k_colstats(const _Float16* __restrict__ x, float* __restrict__ colsum,
                           float* __restrict__ colss) {
  int t = threadIdx.x;
  if (t >= OUTC) return;
  size_t r0 = (size_t)blockIdx.x * 500;
  float s1 = 0.f, s2 = 0.f;
  for (int i = 0; i < 500; ++i) {
    float v = (float)x[(r0 + i) * OUTC + t];
    s1 += v; s2 += v * v;
  }
  atomicAdd(colsum + t, s1);
  atomicAdd(colss + t, s2);
}

// ---------------- x_h = tanh(bn0(xpre)) (f16 -> f16) ----------------
__global__ void k_bn_tanh(const _Float16* __restrict__ x, _Float16* __restrict__ xh,
                          const float* __restrict__ colsum, const float* __restrict__ colss) {
  size_t i = (size_t)blockIdx.x * 256 + threadIdx.x;
  if (i >= 5000000ull) return;  // NENT*OUTC/4
  f16x4 v = ((const f16x4*)x)[i];
  int c = (int)((i * 4) % OUTC);
  const float inv = 1.0f / (float)NENT;
  float m, q, rs;
  f16x4 h;
  m = colsum[c] * inv;     q = colss[c] * inv - m * m;     rs = rsqrtf(q + BN_EPS); h[0] = (_Float16)tanhf(((float)v[0] - m) * rs);
  m = colsum[c + 1] * inv; q = colss[c + 1] * inv - m * m; rs = rsqrtf(q + BN_EPS); h[1] = (_Float16)tanhf(((float)v[1] - m) * rs);
  m = colsum[c + 2] * inv; q = colss[c + 2] * inv - m * m; rs = rsqrtf(q + BN_EPS); h[2] = (_Float16)tanhf(((float)v[2] - m) * rs);
  m = colsum[c + 3] * inv; q = colss[c + 3] * inv - m * m; rs = rsqrtf(q + BN_EPS); h[3] = (_Float16)tanhf(((float)v[3] - m) * rs);
  *(f16x4*)(xh + i * 4) = h;
}

// ---------------- fc_w fp32 -> f16, permuted to k = pos*200+ch ----------
__global__ void __launch_bounds__(256) k_fcw_t(const float* __restrict__ w, _Float16* __restrict__ wh) {
  __shared__ _Float16 tile[50 * 201];
  int blk = blockIdx.x;
  int o = blk >> 2, chq = blk & 3;
  int t = threadIdx.x;
  for (int j = t; j < 50 * POSN; j += 256) {
    int ch = j / POSN, pos = j - ch * POSN;
    tile[ch * 201 + pos] = (_Float16)w[(size_t)o * FCK + (size_t)(chq * 50 + ch) * POSN + pos];
  }
  __syncthreads();
  for (int j = t; j < 50 * POSN; j += 256) {
    int pos = j / 50, ch = j - pos * 50;
    wh[(size_t)o * FCK + (size_t)pos * OUTC + chq * 50 + ch] = tile[ch * 201 + pos];
  }
}

// ---------------- gather ConvE input image (from x_h) + global bn stats ----------------
__global__ void k_gather_img(const _Float16* __restrict__ xh, const float* __restrict__ r,
                             const int* __restrict__ head, const int* __restrict__ rela,
                             float* __restrict__ img, float* __restrict__ bn1) {
  int b = blockIdx.x, t = threadIdx.x;
  int h = head[b], q = rela[b];
  float s1 = 0.f, s2 = 0.f;
  for (int j = t; j < 400; j += 256) {
    float v = (j < OUTC) ? (float)xh[(size_t)h * OUTC + j] : r[(size_t)q * OUTC + (j - OUTC)];
    img[(size_t)b * 400 + j] = v;
    s1 += v; s2 += v * v;
  }
  for (int off = 32; off; off >>= 1) { s1 += __shfl_down(s1, off); s2 += __shfl_down(s2, off); }
  if ((t & 63) == 0) { atomicAdd(bn1, s1); atomicAdd(bn1 + 1, s2); }
}

// ---------------- conv 7x7 valid -> POS-MAJOR f16 z1 [512][196][200] + per-channel stats ----
__global__ void __launch_bounds__(256) k_conv(const float* __restrict__ img, const float* __restrict__ conv_w,
                                              const float* __restrict__ bn1, _Float16* __restrict__ z1,
                                              float* __restrict__ chsum, float* __restrict__ chss) {
  __shared__ float imgn[400];
  int blk = blockIdx.x;
  int b = blk >> 2, q = blk & 3;
  int t = threadIdx.x;
  float m = bn1[0] * (1.0f / 204800.0f);
  float var = bn1[1] * (1.0f / 204800.0f) - m * m;
  float rs = rsqrtf(var + BN_EPS);
  for (int j = t; j < 400; j += 256) imgn[j] = (img[(size_t)b * 400 + j] - m) * rs;
  __syncthreads();
  if (t < OUTC) {
    float w[49];
    #pragma unroll
    for (int i = 0; i < 49; ++i) w[i] = conv_w[t * 49 + i];
    float s1 = 0.f, s2 = 0.f;
    size_t base = (size_t)b * FCK;
    for (int p = 0; p < 49; ++p) {
      int pos = q * 49 + p;
      int y = pos / 14, xx = pos - y * 14;
      float acc = 0.f;
      #pragma unroll
      for (int ky = 0; ky < 7; ++ky)
        #pragma unroll
        for (int kx = 0; kx < 7; ++kx)
          acc += imgn[(y + ky) * 20 + xx + kx] * w[ky * 7 + kx];
      z1[base + (size_t)pos * OUTC + t] = (_Float16)acc;
      s1 += acc; s2 += acc * acc;
    }
    atomicAdd(chsum + t, s1);
    atomicAdd(chss + t, s2);
  }
}

// ---------------- z1 = relu(bn2(z1)) in place (f16, pos-major: c = flat%200) ----------------
__global__ void k_bn2_relu(_Float16* __restrict__ z1, const float* __restrict__ chsum,
                           const float* __restrict__ chss) {
  size_t i = (size_t)blockIdx.x * 256 + threadIdx.x;
  if (i >= 5017600ull) return;  // 512*39200/4
  f16x4 v = ((f16x4*)z1)[i];
  int c = (int)((i * 4) % OUTC);  // 4-aligned within 200
  const float inv = 1.0f / (512.0f * 196.0f);
  #pragma unroll
  for (int e = 0; e < 4; ++e) {
    float m = chsum[c + e] * inv;
    float var = chss[c + e] * inv - m * m;
    float rs = rsqrtf(var + BN_EPS);
    v[e] = (_Float16)fmaxf(((float)v[e] - m) * rs, 0.f);
  }
  ((f16x4*)z1)[i] = v;
}

// ---------------- fc stage 1 via MFMA: partial[ks] (plain stores) ----------------
__global__ void __launch_bounds__(256) k_fc_mfma(const _Float16* __restrict__ A,
                                                 const _Float16* __restrict__ B,
                                                 float* __restrict__ partial) {
  int t = threadIdx.x;
  int w = t >> 6, l = t & 63;
  int lr = l & 15, kg = l >> 4;
  int m0 = blockIdx.y * 128 + w * 32;
  int ks = blockIdx.x;  // 0..174, each 7 k-steps of 32
  f32x4 acc[2][13];
  #pragma unroll
  for (int i = 0; i < 2; ++i)
    #pragma unroll
    for (int j = 0; j < 13; ++j) acc[i][j] = (f32x4){0.f, 0.f, 0.f, 0.f};

  #pragma unroll
  for (int s = 0; s < 7; ++s) {
    int k = (ks * 7 + s) * 32 + kg * 8;
    f16x8 a[2], b[13];
    #pragma unroll
    for (int i = 0; i < 2; ++i)
      a[i] = *(const f16x8*)(A + (size_t)(m0 + i * 16 + lr) * FCK + k);
    #pragma unroll
    for (int j = 0; j < 13; ++j)  // rows 200..207 read in-ws garbage; masked in reduce
      b[j] = *(const f16x8*)(B + (size_t)(j * 16 + lr) * FCK + k);
    #pragma unroll
    for (int i = 0; i < 2; ++i)
      #pragma unroll
      for (int j = 0; j < 13; ++j)
        acc[i][j] = __builtin_amdgcn_mfma_f32_16x16x32_f16(a[i], b[j], acc[i][j], 0, 0, 0);
  }

  float* P = partial + (size_t)ks * FCOUT;
  #pragma unroll
  for (int i = 0; i < 2; ++i) {
    #pragma unroll
    for (int j = 0; j < 13; ++j) {
      int col = j * 16 + lr;
      #pragma unroll
      for (int r = 0; r < 4; ++r) {
        int row = m0 + i * 16 + kg * 4 + r;
        P[(size_t)row * NCOL8 + col] = acc[i][j][r];
      }
    }
  }
}

// ---------------- fc stage 2: reduce over K-splits ----------------
__global__ void __launch_bounds__(256) k_fc_reduce(const float* __restrict__ partial,
                                                   float* __restrict__ z) {
  int i = blockIdx.x * 256 + threadIdx.x;  // 0 .. FCOUT-1 (416*256 == FCOUT)
  float s = 0.f;
  #pragma unroll 5
  for (int ks = 0; ks < KSPLIT; ++ks)
    s += partial[(size_t)ks * FCOUT + i];
  int row = i / NCOL8, col = i - row * NCOL8;
  if (col < OUTC) z[(size_t)row * OUTC + col] = s;
}

// ---------------- z = relu(bn3(z)) -> f16 z_h ----------------
__global__ void k_bn3_relu(const float* __restrict__ z, _Float16* __restrict__ zh) {
  int c = blockIdx.x, lane = threadIdx.x;  // 64 threads
  float v[8];
  float s1 = 0.f, s2 = 0.f;
  #pragma unroll
  for (int i = 0; i < 8; ++i) {
    v[i] = z[(size_t)(lane + i * 64) * OUTC + c];
    s1 += v[i]; s2 += v[i] * v[i];
  }
  for (int off = 32; off; off >>= 1) { s1 += __shfl_down(s1, off); s2 += __shfl_down(s2, off); }
  s1 = __shfl(s1, 0); s2 = __shfl(s2, 0);
  float m = s1 * (1.0f / 512.0f);
  float var = s2 * (1.0f / 512.0f) - m * m;
  float rs = rsqrtf(var + BN_EPS);
  #pragma unroll
  for (int i = 0; i < 8; ++i)
    zh[(size_t)(lane + i * 64) * OUTC + c] = (_Float16)fmaxf((v[i] - m) * rs, 0.f);
}

// ---------------- score = sigmoid(x_h @ z_h.T + b_ent) ----------------
// XCD-aware mapping: xcd = bid&7, idx = bid>>3; 4 m-sub-blocks of a panel run on the
// same XCD -> x_h panel fetched once per XCD L2. Plain f32x4 stores (L2 write-combining).
__global__ void __launch_bounds__(256) k_score_mfma(const _Float16* __restrict__ zh,
                                                    const _Float16* __restrict__ xh,
                                                    const float* __restrict__ b_ent,
                                                    float* __restrict__ out) {
  int bid = blockIdx.x;
  int xcd = bid & 7;
  int idx = bid >> 3;
  int bx = (idx >> 2) * 8 + xcd;
  int by = idx & 3;
  if (bx >= 782) return;
  int t = threadIdx.x;
  int w = t >> 6, l = t & 63;
  int lr = l & 15, kg = l >> 4;
  size_t e0 = (size_t)bx * 128 + w * 32;
  int m0 = by * 128;
  f32x4 acc[2][8];
  #pragma unroll
  for (int i = 0; i < 2; ++i)
    #pragma unroll
    for (int j = 0; j < 8; ++j) acc[i][j] = (f32x4){0.f, 0.f, 0.f, 0.f};

  #pragma unroll
  for (int step = 0; step < 7; ++step) {
    int k = step * 32 + kg * 8;
    bool valid = (k < 200);  // steps 0..5 always true; step 6 only kg==0
    f16x8 a[2], b[8];
    #pragma unroll
    for (int i = 0; i < 2; ++i) {
      size_t row = e0 + i * 16 + lr;
      if (row >= NENT) row = NENT - 1;  // clamp load; store masked
      a[i] = valid ? *(const f16x8*)(xh + row * OUTC + k) : (f16x8)0;
    }
    #pragma unroll
    for (int j = 0; j < 8; ++j) {
      int mrow = m0 + j * 16 + lr;  // always < 512
      b[j] = valid ? *(const f16x8*)(zh + (size_t)mrow * OUTC + k) : (f16x8)0;
    }
    #pragma unroll
    for (int i = 0; i < 2; ++i)
      #pragma unroll
      for (int j = 0; j < 8; ++j)
        acc[i][j] = __builtin_amdgcn_mfma_f32_16x16x32_f16(a[i], b[j], acc[i][j], 0, 0, 0);
  }

  #pragma unroll
  for (int i = 0; i < 2; ++i) {
    size_t e = e0 + i * 16 + kg * 4;  // multiple of 4; NENT%4==0 -> chunk all-valid or all-invalid
    if (e < NENT) {
      float4 be = *(const float4*)(b_ent + e);
      #pragma unroll
      for (int j = 0; j < 8; ++j) {
        int m = m0 + j * 16 + lr;
        f32x4 o;
        o[0] = sigf(acc[i][j][0] + be.x);
        o[1] = sigf(acc[i][j][1] + be.y);
        o[2] = sigf(acc[i][j][2] + be.z);
        o[3] = sigf(acc[i][j][3] + be.w);
        *(f32x4*)(out + (size_t)m * NENT + e) = o;
      }
    }
  }
}

extern "C" void kernel_launch(void* const* d_in, const int* in_sizes, int n_in,
                              void* d_out, int out_size, void* d_ws, size_t ws_size,
                              hipStream_t stream) {
  (void)in_sizes; (void)n_in; (void)out_size; (void)ws_size;
  const float* ent_emb  = (const float*)d_in[0];
  const float* rel_emb  = (const float*)d_in[1];
  const float* in_w     = (const float*)d_in[2];
  const float* out_w    = (const float*)d_in[3];
  const float* loop_w   = (const float*)d_in[4];
  const float* w_rel    = (const float*)d_in[5];
  const float* loop_rel = (const float*)d_in[6];
  // d_in[7] gcn_bias: cancels under axis-0 BN
  const float* edge_norm= (const float*)d_in[8];
  const float* conv_w   = (const float*)d_in[9];
  const float* fc_w     = (const float*)d_in[10];
  // d_in[11] fc_b: cancels under axis-0 BN
  const float* b_ent    = (const float*)d_in[12];
  const int* esrc = (const int*)d_in[13];
  const int* edst = (const int*)d_in[14];
  const int* etyp = (const int*)d_in[15];
  const int* head = (const int*)d_in[16];
  const int* rela = (const int*)d_in[17];
  float* ws  = (float*)d_ws;
  float* out = (float*)d_out;
  int* bk = (int*)(ws + OFF_XBUF);

  // zero: bucket counts + overflow counter, BigBT (f16 pad region), stats
  (void)hipMemsetAsync(bk + BK_CNT, 0, (size_t)(NBUCK + 1) * 4, stream);
  (void)hipMemsetAsync(ws + OFF_BIGBT, 0, (size_t)34944 * 4, stream);
  (void)hipMemsetAsync(ws + OFF_COLSUM, 0, (WS_END - OFF_COLSUM) * 4, stream);

  k_tables<<<20, 256, 0, stream>>>(ws);
  k_dfth<<<56, 256, 0, stream>>>((_Float16*)(ws + OFF_DFTH));
  k_bucket<<<1954, 256, 0, stream>>>(edst, esrc, etyp, edge_norm,
                                     bk + BK_CNT, (uint2*)(bk + BK_SLOT), bk + BK_OVFN, bk + BK_OVF);
  k_rfft_mfma<<<782, 256, 0, stream>>>(ent_emb, (const _Float16*)(ws + OFF_DFTH),
                                       (_Float16*)(ws + OFF_FA));
  k_rfft<<<100, 256, 0, stream>>>(rel_emb, (unsigned int*)(ws + OFF_FB),
                                  ws + OFF_DFTC, ws + OFF_DFTS, NREL);
  k_rfft<<<1, 256, 0, stream>>>(loop_rel, (unsigned int*)(ws + OFF_FL),
                                ws + OFF_DFTC, ws + OFF_DFTS, 1);
  k_wtilde<<<40, 256, 0, stream>>>(in_w, out_w, loop_w, ws);
  k_agg<<<NENT / 2, 256, 0, stream>>>((const unsigned int*)(ws + OFF_FA),
                                      (const unsigned int*)(ws + OFF_FB),
                                      bk + BK_CNT, (const uint2*)(bk + BK_SLOT),
                                      (unsigned int*)(ws + OFF_ACCIN),
                                      (unsigned int*)(ws + OFF_ACCOUT));
  k_ovf<<<64, 256, 0, stream>>>((const unsigned int*)(ws + OFF_FA),
                                (const unsigned int*)(ws + OFF_FB),
                                esrc, edst, etyp, edge_norm,
                                bk + BK_OVFN, bk + BK_OVF,
                                (unsigned int*)(ws + OFF_ACCIN),
                                (unsigned int*)(ws + OFF_ACCOUT));
  k_relmat<<<313, 256, 0, stream>>>(rel_emb, w_rel, ws + OFF_R);
  // xpre f16 overwrites XBUF (bucket arrays dead after k_agg/k_ovf)
  k_fused_x_mfma<<<782, 256, 0, stream>>>(ws, (_Float16*)(ws + OFF_XBUF));
  k_colstats<<<200, 256, 0, stream>>>((const _Float16*)(ws + OFF_XBUF),
                                      ws + OFF_COLSUM, ws + OFF_COLSS);
  k_bn_tanh<<<19532, 256, 0, stream>>>((const _Float16*)(ws + OFF_XBUF), (_Float16*)(ws + OFF_XH),
                                       ws + OFF_COLSUM, ws + OFF_COLSS);
  k_fcw_t<<<800, 256, 0, stream>>>(fc_w, (_Float16*)(ws + OFF_FCWH));
  k_gather_img<<<512, 256, 0, stream>>>((const _Float16*)(ws + OFF_XH), ws + OFF_R,
                                        head, rela, ws + OFF_IMG, ws + OFF_BN1);
  k_conv<<<2048, 256, 0, stream>>>(ws + OFF_IMG, conv_w, ws + OFF_BN1, (_Float16*)(ws + OFF_Z1H),
                                   ws + OFF_CHSUM, ws + OFF_CHSS);
  k_bn2_relu<<<19600, 256, 0, stream>>>((_Float16*)(ws + OFF_Z1H), ws + OFF_CHSUM, ws + OFF_CHSS);
  // fc partials overwrite XBUF (xpre dead after k_bn_tanh)
  k_fc_mfma<<<dim3(KSPLIT, 4), 256, 0, stream>>>((const _Float16*)(ws + OFF_Z1H),
                                                 (const _Float16*)(ws + OFF_FCWH),
                                                 ws + OFF_XBUF);
  k_fc_reduce<<<416, 256, 0, stream>>>(ws + OFF_XBUF, ws + OFF_Z);
  k_bn3_relu<<<200, 64, 0, stream>>>(ws + OFF_Z, (_Float16*)(ws + OFF_ZH));
  k_score_mfma<<<3136, 256, 0, stream>>>((const _Float16*)(ws + OFF_ZH),
                                         (const _Float16*)(ws + OFF_XH),
                                         b_ent, out);
}

// Round 16
// 673.629 us; speedup vs baseline: 1.0666x; 1.0666x over previous
//
#include <hip/hip_runtime.h>

#define NENT  100000
#define NREL  400
#define EMB   100
#define NF    51
#define FCMP  102
#define OUTC  200
#define NEDGE 500000
#define HALFE 250000
#define BATCH 512
#define POSN  196
#define FCK   39200
#define BN_EPS 1e-5f
#define CAP   16
#define KSPLIT 175
#define NCOL8  208   // 13*16 col frags in fc
#define FCOUT  106496  // 512*208

// ---- workspace layout (floats). Peak ~204.3 MB.
// Fa/accIn/accOut: f16 [NENT][102] interleaved (re,im) -> u32 word f = (re_f,im_f).
// z1 is POS-MAJOR [512][196][200] f16 (k = pos*200+ch); fcw_h permuted to match.
// Lifetimes: Fa16 dead after k_fused_x_mfma -> x_h overlays it.
//            accIn dead after k_fused_x_mfma -> z1h (f16) overlays it.
//            accOut dead after k_fused_x_mfma -> fcw_h (f16) overlays it.
//            IMG region: DFTH table (early) -> img (mid) -> z_h (late).
//            XBUF region: bucket ints (early) -> xpre f16 (mid) -> fc partials (late).
static constexpr size_t OFF_FA     = 0;          // [NENT][51] u32 words (f16 cplx)
static constexpr size_t OFF_XH     = 0;          // [NENT][200] f16 overlay
static constexpr size_t OFF_ACCIN  = 10200000;   // [NENT][51] u32 words (f16 cplx)
static constexpr size_t OFF_Z1H    = 10200000;   // [512][196][200] f16 overlay
static constexpr size_t OFF_ACCOUT = 20400000;   // [NENT][51] u32 words (f16 cplx)
static constexpr size_t OFF_FCWH   = 20400000;   // [200][39200] f16 overlay (k = pos*200+ch)
static constexpr size_t OFF_XBUF   = 30600000;   // bucket ints / xpre f16 / fc partials
static constexpr size_t OFF_FB     = 50600000;   // [NREL][51] words
static constexpr size_t OFF_FL     = 50640800;   // [51] words (+pad)
static constexpr size_t OFF_BIGBT  = 50640928;   // [208][336] f16 = 34944 floats (zeroed)
static constexpr size_t OFF_R      = 50675872;   // [400][200]
static constexpr size_t OFF_IMG    = 50755872;   // [512][400]
static constexpr size_t OFF_DFTH   = 50755872;   // [112][128] f16 overlay (early-only)
static constexpr size_t OFF_ZH     = 50755872;   // [512][200] f16 overlay (late)
static constexpr size_t OFF_DFTC   = 50960672;   // [100][51]
static constexpr size_t OFF_DFTS   = 50965772;   // [100][51]
static constexpr size_t OFF_Z      = 50970872;   // [512][200] (written fully by k_fc_reduce)
static constexpr size_t OFF_COLSUM = OFF_Z + 102400;   // memset region starts here
static constexpr size_t OFF_COLSS  = OFF_COLSUM + 200;
static constexpr size_t OFF_BN1    = OFF_COLSS + 200;   // 2 (+pad to 8)
static constexpr size_t OFF_CHSUM  = OFF_BN1 + 8;
static constexpr size_t OFF_CHSS   = OFF_CHSUM + 200;
static constexpr size_t WS_END     = OFF_CHSS + 200;

// bucket layout (ints, base = ws + OFF_XBUF). memset covers CNT+OVFN.
#define NBUCK 200000
static constexpr size_t BK_CNT   = 0;          // [NBUCK]
static constexpr size_t BK_OVFN  = 200000;     // [1]
static constexpr size_t BK_OVF   = 200004;     // [NEDGE] edge-id overflow list (normally empty)
static constexpr size_t BK_SLOT  = 700008;     // uint2[NBUCK*CAP]

typedef __attribute__((ext_vector_type(8))) _Float16 f16x8;
typedef __attribute__((ext_vector_type(4))) _Float16 f16x4;
typedef __attribute__((ext_vector_type(4))) float f32x4;

__device__ inline unsigned int pkc(float re, float im) {
  union { _Float16 h[2]; unsigned int u; } c;
  c.h[0] = (_Float16)re; c.h[1] = (_Float16)im;
  return c.u;
}
__device__ inline float2 unpk(unsigned int w) {
  union { unsigned int u; _Float16 h[2]; } c; c.u = w;
  return make_float2((float)c.h[0], (float)c.h[1]);
}
__device__ inline float sigf(float v) {
  return __builtin_amdgcn_rcpf(1.0f + __expf(-v));
}

// ---------------- DFT twiddle tables (f32, for k_wtilde + small rffts) ----------------
__global__ void k_tables(float* __restrict__ ws) {
  int i = blockIdx.x * 256 + threadIdx.x;
  if (i >= EMB * NF) return;
  int j = i / NF, f = i - j * NF;
  int m = (j * f) % EMB;
  float ang = (float)m * 0.06283185307179586f;  // 2*pi/100
  ws[OFF_DFTC + i] = cosf(ang);
  ws[OFF_DFTS + i] = sinf(ang);
}

// ---------------- DT[112][128] f16 ----------------
__global__ void k_dfth(_Float16* __restrict__ DT) {
  int i = blockIdx.x * 256 + threadIdx.x;
  if (i >= 112 * 128) return;
  int c = i >> 7, k = i & 127;
  float v = 0.f;
  if (c < FCMP && k < EMB) {
    int f = c >> 1;
    int m = (k * f) % EMB;
    float ang = (float)m * 0.06283185307179586f;
    v = (c & 1) ? -sinf(ang) : cosf(ang);
  }
  DT[i] = (_Float16)v;
}

// ---------------- rfft of ent_emb via f16 MFMA ----------------
__global__ void __launch_bounds__(256) k_rfft_mfma(const float* __restrict__ A,
                                                   const _Float16* __restrict__ DT,
                                                   _Float16* __restrict__ Fa) {
  int t = threadIdx.x;
  int w = t >> 6, l = t & 63;
  int lr = l & 15, kg = l >> 4;
  size_t row0 = (size_t)blockIdx.x * 128 + w * 32;
  f32x4 acc[2][7];
  #pragma unroll
  for (int i = 0; i < 2; ++i)
    #pragma unroll
    for (int j = 0; j < 7; ++j) acc[i][j] = (f32x4){0.f, 0.f, 0.f, 0.f};

  #pragma unroll
  for (int st = 0; st < 4; ++st) {
    int koff = st * 32 + kg * 8;
    f16x8 a[2];
    #pragma unroll
    for (int i = 0; i < 2; ++i) {
      size_t row = row0 + i * 16 + lr;
      if (row >= NENT) row = NENT - 1;  // clamp for load; store masked
      f16x8 h;
      if (st < 3) {
        const float* p = A + row * EMB + koff;
        float4 p0 = *(const float4*)p;
        float4 p1 = *(const float4*)(p + 4);
        h[0] = (_Float16)p0.x; h[1] = (_Float16)p0.y; h[2] = (_Float16)p0.z; h[3] = (_Float16)p0.w;
        h[4] = (_Float16)p1.x; h[5] = (_Float16)p1.y; h[6] = (_Float16)p1.z; h[7] = (_Float16)p1.w;
      } else if (kg == 0) {  // k = 96..99 valid
        float4 p0 = *(const float4*)(A + row * EMB + 96);
        h[0] = (_Float16)p0.x; h[1] = (_Float16)p0.y; h[2] = (_Float16)p0.z; h[3] = (_Float16)p0.w;
        h[4] = (_Float16)0.f; h[5] = (_Float16)0.f; h[6] = (_Float16)0.f; h[7] = (_Float16)0.f;
      } else {
        h = (f16x8)0;
      }
      a[i] = h;
    }
    f16x8 b[7];
    #pragma unroll
    for (int j = 0; j < 7; ++j)
      b[j] = *(const f16x8*)(DT + (size_t)(j * 16 + lr) * 128 + koff);
    #pragma unroll
    for (int i = 0; i < 2; ++i)
      #pragma unroll
      for (int j = 0; j < 7; ++j)
        acc[i][j] = __builtin_amdgcn_mfma_f32_16x16x32_f16(a[i], b[j], acc[i][j], 0, 0, 0);
  }

  #pragma unroll
  for (int i = 0; i < 2; ++i) {
    #pragma unroll
    for (int j = 0; j < 7; ++j) {
      int col = j * 16 + lr;
      if (col < FCMP) {
        #pragma unroll
        for (int r = 0; r < 4; ++r) {
          size_t row = row0 + i * 16 + kg * 4 + r;
          if (row < NENT) Fa[row * FCMP + col] = (_Float16)acc[i][j][r];
        }
      }
    }
  }
}

// ---------------- rfft rows -> f16 cplx words (small: rel_emb, loop_rel) ----------------
__global__ void k_rfft(const float* __restrict__ src, unsigned int* __restrict__ dst,
                       const float* __restrict__ dftc, const float* __restrict__ dfts,
                       int nrows) {
  __shared__ float arow[4][EMB];
  int g = threadIdx.x >> 6;
  int lane = threadIdx.x & 63;
  int row = blockIdx.x * 4 + g;
  if (row < nrows) {
    for (int j = lane; j < EMB; j += 64) arow[g][j] = src[(size_t)row * EMB + j];
  }
  __syncthreads();
  if (row < nrows && lane < NF) {
    float re = 0.f, im = 0.f;
    for (int j = 0; j < EMB; ++j) {
      float a = arow[g][j];
      re += a * dftc[j * NF + lane];
      im -= a * dfts[j * NF + lane];
    }
    dst[(size_t)row * NF + lane] = pkc(re, im);
  }
}

// ---------------- fold irfft + weight + 1/3 into BigBT[208][336] f16 ----------------
__global__ void k_wtilde(const float* __restrict__ in_w, const float* __restrict__ out_w,
                         const float* __restrict__ loop_w, float* __restrict__ ws) {
  int id = blockIdx.x * 256 + threadIdx.x;
  if (id >= NF * OUTC) return;
  int f = id / OUTC, o = id - f * OUTC;
  const float* dftc = ws + OFF_DFTC;
  const float* dfts = ws + OFF_DFTS;
  float ci = 0, si = 0, co = 0, so = 0, cl = 0, sl = 0;
  for (int k = 0; k < EMB; ++k) {
    float c = dftc[k * NF + f], s = dfts[k * NF + f];
    float wi = in_w[k * OUTC + o], wo = out_w[k * OUTC + o], wl = loop_w[k * OUTC + o];
    ci += c * wi; si += s * wi;
    co += c * wo; so += s * wo;
    cl += c * wl; sl += s * wl;
  }
  bool ends = (f == 0) || (f == NF - 1);
  float mult = ends ? 1.0f : 2.0f;
  const float inv3n = 1.0f / (3.0f * (float)EMB);
  _Float16* bt = (_Float16*)(ws + OFF_BIGBT);
  size_t ro = (size_t)o * 336;
  bt[ro + 102 + 2 * f]     = (_Float16)(mult * ci * inv3n);
  bt[ro + 102 + 2 * f + 1] = (_Float16)(ends ? 0.f : (-2.0f * si * inv3n));
  bt[ro + 204 + 2 * f]     = (_Float16)(mult * co * inv3n);
  bt[ro + 204 + 2 * f + 1] = (_Float16)(ends ? 0.f : (-2.0f * so * inv3n));
  float wlre = mult * cl * inv3n;
  float wlim = ends ? 0.f : (-2.0f * sl * inv3n);
  float2 fl = unpk(((const unsigned int*)(ws + OFF_FL))[f]);
  bt[ro + 2 * f]     = (_Float16)(fl.x * wlre + fl.y * wlim);
  bt[ro + 2 * f + 1] = (_Float16)(fl.y * wlre - fl.x * wlim);
}

// ---------------- bucket build ----------------
__global__ void k_bucket(const int* __restrict__ edst, const int* __restrict__ esrc,
                         const int* __restrict__ etyp, const float* __restrict__ enorm,
                         int* __restrict__ cnt, uint2* __restrict__ slot,
                         int* __restrict__ ovfn, int* __restrict__ ovf) {
  int e = blockIdx.x * 256 + threadIdx.x;
  if (e >= NEDGE) return;
  int b = (e < HALFE ? 0 : NENT) + edst[e];
  int pos = atomicAdd(&cnt[b], 1);
  if (pos < CAP) {
    unsigned int p = (unsigned int)esrc[e] | ((unsigned int)etyp[e] << 17);
    slot[(size_t)b * CAP + pos] = make_uint2(p, __float_as_uint(enorm[e]));
  } else {  // statistically ~never; correctness fallback
    int oi = atomicAdd(ovfn, 1);
    if (oi < NEDGE) ovf[oi] = e;
  }
}

// ---------------- gather-aggregate (no atomics), 4-deep MLP unroll, f16 packed output ------
__global__ void __launch_bounds__(256) k_agg(const unsigned int* __restrict__ faw,
                                             const unsigned int* __restrict__ fbw,
                                             const int* __restrict__ cnt,
                                             const uint2* __restrict__ slot,
                                             unsigned int* __restrict__ accIn,
                                             unsigned int* __restrict__ accOut) {
  int g = threadIdx.x >> 6;          // 4 waves: (d0,in),(d0,out),(d0+1,in),(d0+1,out)
  int lane = threadIdx.x & 63;
  int d = blockIdx.x * 2 + (g >> 1);
  int sub = g & 1;
  int bucket = sub * NENT + d;
  int n = cnt[bucket];
  if (n > CAP) n = CAP;
  const uint2* sl = slot + (size_t)bucket * CAP;
  uint2 my = make_uint2(0u, 0u);
  if (lane < n) my = sl[lane];       // lane-parallel slot prefetch
  float ar = 0.f, ai = 0.f;
  for (int i = 0; i < n; i += 4) {   // 4-wide: loads for u=0..3 independent -> 4-deep MLP
    #pragma unroll
    for (int u = 0; u < 4; ++u) {
      int iu = i + u;
      int ic = (iu < n) ? iu : (n - 1);          // clamp (n>=1 inside loop)
      unsigned int p = (unsigned int)__shfl((int)my.x, ic);
      float nor = __uint_as_float((unsigned int)__shfl((int)my.y, ic));
      if (iu >= n) nor = 0.f;                    // mask duplicates
      int s = (int)(p & 0x1FFFFu);
      int ty = (int)(p >> 17);
      if (lane < NF) {
        float2 fa = unpk(faw[(size_t)s * NF + lane]);
        float2 fb = unpk(fbw[(size_t)ty * NF + lane]);
        ar += (fa.x * fb.x + fa.y * fb.y) * nor;  // conj(Fa)*Fb real
        ai += (fa.x * fb.y - fa.y * fb.x) * nor;  // imag
      }
    }
  }
  if (lane < NF) {
    unsigned int* dst = sub ? accOut : accIn;
    dst[(size_t)d * NF + lane] = pkc(ar, ai);
  }
}

// ---------------- overflow replay (normally empty): CAS add on packed f16 words ----------------
__global__ void k_ovf(const unsigned int* __restrict__ faw, const unsigned int* __restrict__ fbw,
                      const int* __restrict__ esrc, const int* __restrict__ edst,
                      const int* __restrict__ etyp, const float* __restrict__ enorm,
                      const int* __restrict__ ovfn, const int* __restrict__ ovf,
                      unsigned int* __restrict__ accIn, unsigned int* __restrict__ accOut) {
  int sub = threadIdx.x >> 6;
  int l = threadIdx.x & 63;
  if (l >= NF) return;
  int n = *ovfn;
  if (n > NEDGE) n = NEDGE;
  for (int j = blockIdx.x * 4 + sub; j < n; j += gridDim.x * 4) {
    int e = ovf[j];
    int s = esrc[e], d = edst[e], ty = etyp[e];
    float nor = enorm[e];
    float2 fa = unpk(faw[(size_t)s * NF + l]);
    float2 fb = unpk(fbw[(size_t)ty * NF + l]);
    float vr = (fa.x * fb.x + fa.y * fb.y) * nor;
    float vi = (fa.x * fb.y - fa.y * fb.x) * nor;
    unsigned int* addr = ((e < HALFE) ? accIn : accOut) + (size_t)d * NF + l;
    unsigned int old = *addr, assumed;
    do {
      assumed = old;
      float2 cur = unpk(assumed);
      old = atomicCAS(addr, assumed, pkc(cur.x + vr, cur.y + vi));
    } while (old != assumed);
  }
}

// ---------------- r = rel_emb @ w_rel ----------------
__global__ void k_relmat(const float* __restrict__ rel_emb, const float* __restrict__ w_rel,
                         float* __restrict__ r) {
  int id = blockIdx.x * 256 + threadIdx.x;
  if (id >= NREL * OUTC) return;
  int rr = id / OUTC, o = id - rr * OUTC;
  float acc = 0.f;
  for (int k = 0; k < EMB; ++k) acc += rel_emb[rr * EMB + k] * w_rel[k * OUTC + o];
  r[id] = acc;
}

// ---------------- x_pre = [Fa16 | accIn16 | accOut16] @ BigBT.T via f16 MFMA -> f16 xpre ------
__global__ void __launch_bounds__(256) k_fused_x_mfma(const float* __restrict__ ws,
                                                      _Float16* __restrict__ xpre) {
  int t = threadIdx.x;
  int w = t >> 6, l = t & 63;
  int lr = l & 15, kg = l >> 4;
  size_t row0 = (size_t)blockIdx.x * 128 + w * 32;
  const _Float16* BT = (const _Float16*)(ws + OFF_BIGBT);
  const _Float16* segp[3] = {(const _Float16*)(ws + OFF_FA),
                             (const _Float16*)(ws + OFF_ACCIN),
                             (const _Float16*)(ws + OFF_ACCOUT)};
  f32x4 acc[2][13];
  #pragma unroll
  for (int i = 0; i < 2; ++i)
    #pragma unroll
    for (int j = 0; j < 13; ++j) acc[i][j] = (f32x4){0.f, 0.f, 0.f, 0.f};

  #pragma unroll
  for (int seg = 0; seg < 3; ++seg) {
    const _Float16* P = segp[seg];
    #pragma unroll
    for (int st = 0; st < 4; ++st) {
      int koff = st * 32 + kg * 8;
      f16x8 a[2];
      #pragma unroll
      for (int i = 0; i < 2; ++i) {
        size_t row = row0 + i * 16 + lr;
        f16x8 h = *(const f16x8*)(P + row * FCMP + koff);
        if (st == 3) {
          #pragma unroll
          for (int e = 0; e < 8; ++e)
            if (koff + e >= FCMP) h[e] = (_Float16)0.f;
        }
        a[i] = h;
      }
      f16x8 b[13];
      #pragma unroll
      for (int j = 0; j < 13; ++j)
        b[j] = *(const f16x8*)(BT + (size_t)(j * 16 + lr) * 336 + seg * FCMP + koff);
      #pragma unroll
      for (int i = 0; i < 2; ++i)
        #pragma unroll
        for (int j = 0; j < 13; ++j)
          acc[i][j] = __builtin_amdgcn_mfma_f32_16x16x32_f16(a[i], b[j], acc[i][j], 0, 0, 0);
    }
  }

  #pragma unroll
  for (int i = 0; i < 2; ++i) {
    #pragma unroll
    for (int j = 0; j < 13; ++j) {
      int col = j * 16 + lr;
      if (col < OUTC) {
        #pragma unroll
        for (int r = 0; r < 4; ++r) {
          size_t row = row0 + i * 16 + kg * 4 + r;
          if (row < NENT) xpre[row * OUTC + col] = (_Float16)acc[i][j][r];
        }
      }
    }
  }
}

// ---------------- column stats of xpre (f16) ----------------
__global__ void k_colstats(const _Float16* __restrict__ x, float* __restrict__ colsum,
                           float* __restrict__ colss) {
  int t = threadIdx.x;
  if (t >= OUTC) return;
  size_t r0 = (size_t)blockIdx.x * 500;
  float s1 = 0.f, s2 = 0.f;
  for (int i = 0; i < 500; ++i) {
    float v = (float)x[(r0 + i) * OUTC + t];
    s1 += v; s2 += v * v;
  }
  atomicAdd(colsum + t, s1);
  atomicAdd(colss + t, s2);
}

// ---------------- x_h = tanh(bn0(xpre)) (f16 -> f16) ----------------
__global__ void k_bn_tanh(const _Float16* __restrict__ x, _Float16* __restrict__ xh,
                          const float* __restrict__ colsum, const float* __restrict__ colss) {
  size_t i = (size_t)blockIdx.x * 256 + threadIdx.x;
  if (i >= 5000000ull) return;  // NENT*OUTC/4
  f16x4 v = ((const f16x4*)x)[i];
  int c = (int)((i * 4) % OUTC);
  const float inv = 1.0f / (float)NENT;
  float m, q, rs;
  f16x4 h;
  m = colsum[c] * inv;     q = colss[c] * inv - m * m;     rs = rsqrtf(q + BN_EPS); h[0] = (_Float16)tanhf(((float)v[0] - m) * rs);
  m = colsum[c + 1] * inv; q = colss[c + 1] * inv - m * m; rs = rsqrtf(q + BN_EPS); h[1] = (_Float16)tanhf(((float)v[1] - m) * rs);
  m = colsum[c + 2] * inv; q = colss[c + 2] * inv - m * m; rs = rsqrtf(q + BN_EPS); h[2] = (_Float16)tanhf(((float)v[2] - m) * rs);
  m = colsum[c + 3] * inv; q = colss[c + 3] * inv - m * m; rs = rsqrtf(q + BN_EPS); h[3] = (_Float16)tanhf(((float)v[3] - m) * rs);
  *(f16x4*)(xh + i * 4) = h;
}

// ---------------- fc_w fp32 -> f16, permuted to k = pos*200+ch ----------
__global__ void __launch_bounds__(256) k_fcw_t(const float* __restrict__ w, _Float16* __restrict__ wh) {
  __shared__ _Float16 tile[50 * 201];
  int blk = blockIdx.x;
  int o = blk >> 2, chq = blk & 3;
  int t = threadIdx.x;
  for (int j = t; j < 50 * POSN; j += 256) {
    int ch = j / POSN, pos = j - ch * POSN;
    tile[ch * 201 + pos] = (_Float16)w[(size_t)o * FCK + (size_t)(chq * 50 + ch) * POSN + pos];
  }
  __syncthreads();
  for (int j = t; j < 50 * POSN; j += 256) {
    int pos = j / 50, ch = j - pos * 50;
    wh[(size_t)o * FCK + (size_t)pos * OUTC + chq * 50 + ch] = tile[ch * 201 + pos];
  }
}

// ---------------- gather ConvE input image (from x_h) + global bn stats ----------------
__global__ void k_gather_img(const _Float16* __restrict__ xh, const float* __restrict__ r,
                             const int* __restrict__ head, const int* __restrict__ rela,
                             float* __restrict__ img, float* __restrict__ bn1) {
  int b = blockIdx.x, t = threadIdx.x;
  int h = head[b], q = rela[b];
  float s1 = 0.f, s2 = 0.f;
  for (int j = t; j < 400; j += 256) {
    float v = (j < OUTC) ? (float)xh[(size_t)h * OUTC + j] : r[(size_t)q * OUTC + (j - OUTC)];
    img[(size_t)b * 400 + j] = v;
    s1 += v; s2 += v * v;
  }
  for (int off = 32; off; off >>= 1) { s1 += __shfl_down(s1, off); s2 += __shfl_down(s2, off); }
  if ((t & 63) == 0) { atomicAdd(bn1, s1); atomicAdd(bn1 + 1, s2); }
}

// ---------------- conv 7x7 valid -> POS-MAJOR f16 z1 [512][196][200] + per-channel stats ----
__global__ void __launch_bounds__(256) k_conv(const float* __restrict__ img, const float* __restrict__ conv_w,
                                              const float* __restrict__ bn1, _Float16* __restrict__ z1,
                                              float* __restrict__ chsum, float* __restrict__ chss) {
  __shared__ float imgn[400];
  int blk = blockIdx.x;
  int b = blk >> 2, q = blk & 3;
  int t = threadIdx.x;
  float m = bn1[0] * (1.0f / 204800.0f);
  float var = bn1[1] * (1.0f / 204800.0f) - m * m;
  float rs = rsqrtf(var + BN_EPS);
  for (int j = t; j < 400; j += 256) imgn[j] = (img[(size_t)b * 400 + j] - m) * rs;
  __syncthreads();
  if (t < OUTC) {
    float w[49];
    #pragma unroll
    for (int i = 0; i < 49; ++i) w[i] = conv_w[t * 49 + i];
    float s1 = 0.f, s2 = 0.f;
    size_t base = (size_t)b * FCK;
    for (int p = 0; p < 49; ++p) {
      int pos = q * 49 + p;
      int y = pos / 14, xx = pos - y * 14;
      float acc = 0.f;
      #pragma unroll
      for (int ky = 0; ky < 7; ++ky)
        #pragma unroll
        for (int kx = 0; kx < 7; ++kx)
          acc += imgn[(y + ky) * 20 + xx + kx] * w[ky * 7 + kx];
      z1[base + (size_t)pos * OUTC + t] = (_Float16)acc;
      s1 += acc; s2 += acc * acc;
    }
    atomicAdd(chsum + t, s1);
    atomicAdd(chss + t, s2);
  }
}

// ---------------- z1 = relu(bn2(z1)) in place (f16, pos-major: c = flat%200) ----------------
__global__ void k_bn2_relu(_Float16* __restrict__ z1, const float* __restrict__ chsum,
                           const float* __restrict__ chss) {
  size_t i = (size_t)blockIdx.x * 256 + threadIdx.x;
  if (i >= 5017600ull) return;  // 512*39200/4
  f16x4 v = ((f16x4*)z1)[i];
  int c = (int)((i * 4) % OUTC);  // 4-aligned within 200
  const float inv = 1.0f / (512.0f * 196.0f);
  #pragma unroll
  for (int e = 0; e < 4; ++e) {
    float m = chsum[c + e] * inv;
    float var = chss[c + e] * inv - m * m;
    float rs = rsqrtf(var + BN_EPS);
    v[e] = (_Float16)fmaxf(((float)v[e] - m) * rs, 0.f);
  }
  ((f16x4*)z1)[i] = v;
}

// ---------------- fc stage 1 via MFMA: partial[ks] (plain stores) ----------------
__global__ void __launch_bounds__(256) k_fc_mfma(const _Float16* __restrict__ A,
                                                 const _Float16* __restrict__ B,
                                                 float* __restrict__ partial) {
  int t = threadIdx.x;
  int w = t >> 6, l = t & 63;
  int lr = l & 15, kg = l >> 4;
  int m0 = blockIdx.y * 128 + w * 32;
  int ks = blockIdx.x;  // 0..174, each 7 k-steps of 32
  f32x4 acc[2][13];
  #pragma unroll
  for (int i = 0; i < 2; ++i)
    #pragma unroll
    for (int j = 0; j < 13; ++j) acc[i][j] = (f32x4){0.f, 0.f, 0.f, 0.f};

  #pragma unroll
  for (int s = 0; s < 7; ++s) {
    int k = (ks * 7 + s) * 32 + kg * 8;
    f16x8 a[2], b[13];
    #pragma unroll
    for (int i = 0; i < 2; ++i)
      a[i] = *(const f16x8*)(A + (size_t)(m0 + i * 16 + lr) * FCK + k);
    #pragma unroll
    for (int j = 0; j < 13; ++j)  // rows 200..207 read in-ws garbage; masked in reduce
      b[j] = *(const f16x8*)(B + (size_t)(j * 16 + lr) * FCK + k);
    #pragma unroll
    for (int i = 0; i < 2; ++i)
      #pragma unroll
      for (int j = 0; j < 13; ++j)
        acc[i][j] = __builtin_amdgcn_mfma_f32_16x16x32_f16(a[i], b[j], acc[i][j], 0, 0, 0);
  }

  float* P = partial + (size_t)ks * FCOUT;
  #pragma unroll
  for (int i = 0; i < 2; ++i) {
    #pragma unroll
    for (int j = 0; j < 13; ++j) {
      int col = j * 16 + lr;
      #pragma unroll
      for (int r = 0; r < 4; ++r) {
        int row = m0 + i * 16 + kg * 4 + r;
        P[(size_t)row * NCOL8 + col] = acc[i][j][r];
      }
    }
  }
}

// ---------------- fc stage 2: reduce over K-splits ----------------
__global__ void __launch_bounds__(256) k_fc_reduce(const float* __restrict__ partial,
                                                   float* __restrict__ z) {
  int i = blockIdx.x * 256 + threadIdx.x;  // 0 .. FCOUT-1 (416*256 == FCOUT)
  float s = 0.f;
  #pragma unroll 5
  for (int ks = 0; ks < KSPLIT; ++ks)
    s += partial[(size_t)ks * FCOUT + i];
  int row = i / NCOL8, col = i - row * NCOL8;
  if (col < OUTC) z[(size_t)row * OUTC + col] = s;
}

// ---------------- z = relu(bn3(z)) -> f16 z_h ----------------
__global__ void k_bn3_relu(const float* __restrict__ z, _Float16* __restrict__ zh) {
  int c = blockIdx.x, lane = threadIdx.x;  // 64 threads
  float v[8];
  float s1 = 0.f, s2 = 0.f;
  #pragma unroll
  for (int i = 0; i < 8; ++i) {
    v[i] = z[(size_t)(lane + i * 64) * OUTC + c];
    s1 += v[i]; s2 += v[i] * v[i];
  }
  for (int off = 32; off; off >>= 1) { s1 += __shfl_down(s1, off); s2 += __shfl_down(s2, off); }
  s1 = __shfl(s1, 0); s2 = __shfl(s2, 0);
  float m = s1 * (1.0f / 512.0f);
  float var = s2 * (1.0f / 512.0f) - m * m;
  float rs = rsqrtf(var + BN_EPS);
  #pragma unroll
  for (int i = 0; i < 8; ++i)
    zh[(size_t)(lane + i * 64) * OUTC + c] = (_Float16)fmaxf((v[i] - m) * rs, 0.f);
}

// ---------------- score = sigmoid(x_h @ z_h.T + b_ent) ----------------
// XCD-aware, double-concurrency: xcd = bid&7, idx = bid>>3, by = idx&7 (64-row m-tile),
// bx = (idx>>3)*8 + xcd. All 8 m-siblings of an x_h panel run consecutively on one XCD.
// Nontemporal f32x4 stores (R13-verified best). Grid 8*8*98 = 6272; tail bx>=782 exits.
__global__ void __launch_bounds__(256) k_score_mfma(const _Float16* __restrict__ zh,
                                                    const _Float16* __restrict__ xh,
                                                    const float* __restrict__ b_ent,
                                                    float* __restrict__ out) {
  int bid = blockIdx.x;
  int xcd = bid & 7;
  int idx = bid >> 3;
  int by = idx & 7;
  int bx = (idx >> 3) * 8 + xcd;
  if (bx >= 782) return;
  int t = threadIdx.x;
  int w = t >> 6, l = t & 63;
  int lr = l & 15, kg = l >> 4;
  size_t e0 = (size_t)bx * 128 + w * 32;
  int m0 = by * 64;
  f32x4 acc[2][4];
  #pragma unroll
  for (int i = 0; i < 2; ++i)
    #pragma unroll
    for (int j = 0; j < 4; ++j) acc[i][j] = (f32x4){0.f, 0.f, 0.f, 0.f};

  #pragma unroll
  for (int step = 0; step < 7; ++step) {
    int k = step * 32 + kg * 8;
    bool valid = (k < 200);  // steps 0..5 always true; step 6 only kg==0
    f16x8 a[2], b[4];
    #pragma unroll
    for (int i = 0; i < 2; ++i) {
      size_t row = e0 + i * 16 + lr;
      if (row >= NENT) row = NENT - 1;  // clamp load; store masked
      a[i] = valid ? *(const f16x8*)(xh + row * OUTC + k) : (f16x8)0;
    }
    #pragma unroll
    for (int j = 0; j < 4; ++j) {
      int mrow = m0 + j * 16 + lr;  // always < 512
      b[j] = valid ? *(const f16x8*)(zh + (size_t)mrow * OUTC + k) : (f16x8)0;
    }
    #pragma unroll
    for (int i = 0; i < 2; ++i)
      #pragma unroll
      for (int j = 0; j < 4; ++j)
        acc[i][j] = __builtin_amdgcn_mfma_f32_16x16x32_f16(a[i], b[j], acc[i][j], 0, 0, 0);
  }

  #pragma unroll
  for (int i = 0; i < 2; ++i) {
    size_t e = e0 + i * 16 + kg * 4;  // multiple of 4; NENT%4==0 -> chunk all-valid or all-invalid
    if (e < NENT) {
      float4 be = *(const float4*)(b_ent + e);
      #pragma unroll
      for (int j = 0; j < 4; ++j) {
        int m = m0 + j * 16 + lr;
        f32x4 o;
        o[0] = sigf(acc[i][j][0] + be.x);
        o[1] = sigf(acc[i][j][1] + be.y);
        o[2] = sigf(acc[i][j][2] + be.z);
        o[3] = sigf(acc[i][j][3] + be.w);
        __builtin_nontemporal_store(o, (f32x4*)(out + (size_t)m * NENT + e));
      }
    }
  }
}

extern "C" void kernel_launch(void* const* d_in, const int* in_sizes, int n_in,
                              void* d_out, int out_size, void* d_ws, size_t ws_size,
                              hipStream_t stream) {
  (void)in_sizes; (void)n_in; (void)out_size; (void)ws_size;
  const float* ent_emb  = (const float*)d_in[0];
  const float* rel_emb  = (const float*)d_in[1];
  const float* in_w     = (const float*)d_in[2];
  const float* out_w    = (const float*)d_in[3];
  const float* loop_w   = (const float*)d_in[4];
  const float* w_rel    = (const float*)d_in[5];
  const float* loop_rel = (const float*)d_in[6];
  // d_in[7] gcn_bias: cancels under axis-0 BN
  const float* edge_norm= (const float*)d_in[8];
  const float* conv_w   = (const float*)d_in[9];
  const float* fc_w     = (const float*)d_in[10];
  // d_in[11] fc_b: cancels under axis-0 BN
  const float* b_ent    = (const float*)d_in[12];
  const int* esrc = (const int*)d_in[13];
  const int* edst = (const int*)d_in[14];
  const int* etyp = (const int*)d_in[15];
  const int* head = (const int*)d_in[16];
  const int* rela = (const int*)d_in[17];
  float* ws  = (float*)d_ws;
  float* out = (float*)d_out;
  int* bk = (int*)(ws + OFF_XBUF);

  // zero: bucket counts + overflow counter, BigBT (f16 pad region), stats
  (void)hipMemsetAsync(bk + BK_CNT, 0, (size_t)(NBUCK + 1) * 4, stream);
  (void)hipMemsetAsync(ws + OFF_BIGBT, 0, (size_t)34944 * 4, stream);
  (void)hipMemsetAsync(ws + OFF_COLSUM, 0, (WS_END - OFF_COLSUM) * 4, stream);

  k_tables<<<20, 256, 0, stream>>>(ws);
  k_dfth<<<56, 256, 0, stream>>>((_Float16*)(ws + OFF_DFTH));
  k_bucket<<<1954, 256, 0, stream>>>(edst, esrc, etyp, edge_norm,
                                     bk + BK_CNT, (uint2*)(bk + BK_SLOT), bk + BK_OVFN, bk + BK_OVF);
  k_rfft_mfma<<<782, 256, 0, stream>>>(ent_emb, (const _Float16*)(ws + OFF_DFTH),
                                       (_Float16*)(ws + OFF_FA));
  k_rfft<<<100, 256, 0, stream>>>(rel_emb, (unsigned int*)(ws + OFF_FB),
                                  ws + OFF_DFTC, ws + OFF_DFTS, NREL);
  k_rfft<<<1, 256, 0, stream>>>(loop_rel, (unsigned int*)(ws + OFF_FL),
                                ws + OFF_DFTC, ws + OFF_DFTS, 1);
  k_wtilde<<<40, 256, 0, stream>>>(in_w, out_w, loop_w, ws);
  k_agg<<<NENT / 2, 256, 0, stream>>>((const unsigned int*)(ws + OFF_FA),
                                      (const unsigned int*)(ws + OFF_FB),
                                      bk + BK_CNT, (const uint2*)(bk + BK_SLOT),
                                      (unsigned int*)(ws + OFF_ACCIN),
                                      (unsigned int*)(ws + OFF_ACCOUT));
  k_ovf<<<64, 256, 0, stream>>>((const unsigned int*)(ws + OFF_FA),
                                (const unsigned int*)(ws + OFF_FB),
                                esrc, edst, etyp, edge_norm,
                                bk + BK_OVFN, bk + BK_OVF,
                                (unsigned int*)(ws + OFF_ACCIN),
                                (unsigned int*)(ws + OFF_ACCOUT));
  k_relmat<<<313, 256, 0, stream>>>(rel_emb, w_rel, ws + OFF_R);
  // xpre f16 overwrites XBUF (bucket arrays dead after k_agg/k_ovf)
  k_fused_x_mfma<<<782, 256, 0, stream>>>(ws, (_Float16*)(ws + OFF_XBUF));
  k_colstats<<<200, 256, 0, stream>>>((const _Float16*)(ws + OFF_XBUF),
                                      ws + OFF_COLSUM, ws + OFF_COLSS);
  k_bn_tanh<<<19532, 256, 0, stream>>>((const _Float16*)(ws + OFF_XBUF), (_Float16*)(ws + OFF_XH),
                                       ws + OFF_COLSUM, ws + OFF_COLSS);
  k_fcw_t<<<800, 256, 0, stream>>>(fc_w, (_Float16*)(ws + OFF_FCWH));
  k_gather_img<<<512, 256, 0, stream>>>((const _Float16*)(ws + OFF_XH), ws + OFF_R,
                                        head, rela, ws + OFF_IMG, ws + OFF_BN1);
  k_conv<<<2048, 256, 0, stream>>>(ws + OFF_IMG, conv_w, ws + OFF_BN1, (_Float16*)(ws + OFF_Z1H),
                                   ws + OFF_CHSUM, ws + OFF_CHSS);
  k_bn2_relu<<<19600, 256, 0, stream>>>((_Float16*)(ws + OFF_Z1H), ws + OFF_CHSUM, ws + OFF_CHSS);
  // fc partials overwrite XBUF (xpre dead after k_bn_tanh)
  k_fc_mfma<<<dim3(KSPLIT, 4), 256, 0, stream>>>((const _Float16*)(ws + OFF_Z1H),
                                                 (const _Float16*)(ws + OFF_FCWH),
                                                 ws + OFF_XBUF);
  k_fc_reduce<<<416, 256, 0, stream>>>(ws + OFF_XBUF, ws + OFF_Z);
  k_bn3_relu<<<200, 64, 0, stream>>>(ws + OFF_Z, (_Float16*)(ws + OFF_ZH));
  k_score_mfma<<<6272, 256, 0, stream>>>((const _Float16*)(ws + OFF_ZH),
                                         (const _Float16*)(ws + OFF_XH),
                                         b_ent, out);
}